// Round 1
// baseline (336.621 us; speedup 1.0000x reference)
//
#include <hip/hip_runtime.h>

#define HID 768
#define NL  17
#define BB  64
#define TT  512

// ---------------------------------------------------------------------------
// Kernel 1: emissions = outputs @ fc_w^T + fc_b
// One lane per output row (b*t). Weights addressed uniformly -> s_load.
// ---------------------------------------------------------------------------
__global__ __launch_bounds__(64) void emis_kernel(const float* __restrict__ x,
                                                  const float* __restrict__ w,
                                                  const float* __restrict__ bias,
                                                  float* __restrict__ y) {
    const int row = blockIdx.x * 64 + threadIdx.x;   // 0 .. 32767
    const float* rp = x + (size_t)row * HID;

    float acc[NL];
#pragma unroll
    for (int k = 0; k < NL; ++k) acc[k] = bias[k];

#pragma unroll 1
    for (int it = 0; it < HID; it += 64) {
        float4 r[16];
#pragma unroll
        for (int u = 0; u < 16; ++u)
            r[u] = *reinterpret_cast<const float4*>(rp + it + u * 4);
#pragma unroll
        for (int k = 0; k < NL; ++k) {
            float s0 = 0.f, s1 = 0.f, s2 = 0.f, s3 = 0.f;
#pragma unroll
            for (int u = 0; u < 16; ++u) {
                const float4 wv = *reinterpret_cast<const float4*>(w + k * HID + it + u * 4);
                s0 = fmaf(r[u].x, wv.x, s0);
                s1 = fmaf(r[u].y, wv.y, s1);
                s2 = fmaf(r[u].z, wv.z, s2);
                s3 = fmaf(r[u].w, wv.w, s3);
            }
            acc[k] += (s0 + s1) + (s2 + s3);
        }
    }

    float* yp = y + (size_t)row * NL;
#pragma unroll
    for (int k = 0; k < NL; ++k) yp[k] = acc[k];
}

// ---------------------------------------------------------------------------
// Kernel 2: per-batch CRF log-likelihood. One wave (64 threads) per batch.
// Forward scan in the exp domain: p' = (E^t p) * exp(em_t), E^t = exp(trans).
// ---------------------------------------------------------------------------
__device__ __forceinline__ float bcast(float v, int lane) {
    return __uint_as_float(__builtin_amdgcn_readlane(__float_as_uint(v), lane));
}

__global__ __launch_bounds__(64) void crf_kernel(const float* __restrict__ emis,
                                                 const float* __restrict__ start_t,
                                                 const float* __restrict__ end_t,
                                                 const float* __restrict__ trans,
                                                 const int* __restrict__ labels,
                                                 const int* __restrict__ mask,
                                                 float* __restrict__ llh) {
    __shared__ float em_s[TT * NL];      // 34.8 KB: this batch's emissions
    __shared__ float trans_s[NL * NL];

    const int b = blockIdx.x;
    const int l = threadIdx.x;

    // stage emissions + trans into LDS (coalesced float4 copies)
    const float4* eb4 = reinterpret_cast<const float4*>(emis + (size_t)b * TT * NL);
    float4* em4 = reinterpret_cast<float4*>(em_s);
    for (int i = l; i < TT * NL / 4; i += 64) em4[i] = eb4[i];
    for (int i = l; i < NL * NL; i += 64) trans_s[i] = trans[i];
    __syncthreads();

    // sequence length (mask is a prefix; reference forces mask[:,0]=True)
    int lenp = 0;
    for (int i = l; i < TT; i += 64) lenp += (mask[b * TT + i] != 0);
#pragma unroll
    for (int off = 32; off; off >>= 1) lenp += __shfl_down(lenp, off);
    const int len = __shfl(lenp, 0);

    // ---------------- numerator ----------------
    float np = 0.f;
    for (int t = l; t < len; t += 64) {
        int tag = labels[b * TT + t];
        if (tag < 0 || tag >= NL) tag = 0;
        if (t == 0) {
            np += start_t[tag] + em_s[tag];
        } else {
            int tp = labels[b * TT + t - 1];
            if (tp < 0 || tp >= NL) tp = 0;
            np += trans_s[tp * NL + tag] + em_s[t * NL + tag];
        }
        if (t == len - 1) np += end_t[tag];
    }
#pragma unroll
    for (int off = 32; off; off >>= 1) np += __shfl_down(np, off);
    const float num = __shfl(np, 0);

    // ---------------- denominator: forward scan, exp domain ----------------
    const bool act = (l < NL);
    const int  j   = act ? l : 0;

    float et[NL];                        // exp(trans[i][j]) for my column j
#pragma unroll
    for (int i = 0; i < NL; ++i) et[i] = __expf(trans_s[i * NL + j]);

    float p = act ? __expf(start_t[j] + em_s[j]) : 0.f;   // score[0][j], exp domain
    float M = 0.f;                                        // accumulated log offset

    for (int t = 1; t < len; ++t) {
        const float eem = act ? __expf(em_s[t * NL + j]) : 0.f;
        float q0 = 0.f, q1 = 0.f, q2 = 0.f, q3 = 0.f;
#pragma unroll
        for (int i = 0; i < 16; i += 4) {
            q0 = fmaf(bcast(p, i + 0), et[i + 0], q0);
            q1 = fmaf(bcast(p, i + 1), et[i + 1], q1);
            q2 = fmaf(bcast(p, i + 2), et[i + 2], q2);
            q3 = fmaf(bcast(p, i + 3), et[i + 3], q3);
        }
        q0 = fmaf(bcast(p, 16), et[16], q0);
        p = ((q0 + q1) + (q2 + q3)) * eem;

        if ((t & 3) == 0) {              // renormalize every 4 steps
            const float p0 = bcast(p, 0);
            M += __logf(p0);
            p *= __frcp_rn(p0);
        }
    }

    float v = act ? p * __expf(end_t[j]) : 0.f;
#pragma unroll
    for (int off = 32; off; off >>= 1) v += __shfl_down(v, off);

    if (l == 0) {
        const float denom = M + __logf(v);
        llh[b] = num - denom;
    }
}

// ---------------------------------------------------------------------------
// Kernel 3: loss = -mean(llh)
// ---------------------------------------------------------------------------
__global__ __launch_bounds__(64) void loss_kernel(const float* __restrict__ llh,
                                                  float* __restrict__ loss) {
    float v = llh[threadIdx.x];
#pragma unroll
    for (int off = 32; off; off >>= 1) v += __shfl_down(v, off);
    if (threadIdx.x == 0) loss[0] = -(v * (1.0f / BB));
}

// ---------------------------------------------------------------------------
extern "C" void kernel_launch(void* const* d_in, const int* in_sizes, int n_in,
                              void* d_out, int out_size, void* d_ws, size_t ws_size,
                              hipStream_t stream) {
    const float* outputs = (const float*)d_in[0];
    const float* fc_w    = (const float*)d_in[1];
    const float* fc_b    = (const float*)d_in[2];
    const float* start_t = (const float*)d_in[3];
    const float* end_t   = (const float*)d_in[4];
    const float* trans   = (const float*)d_in[5];
    const int*   labels  = (const int*)d_in[6];
    const int*   mask    = (const int*)d_in[7];

    float* emis = (float*)d_out;
    float* loss = emis + (size_t)BB * TT * NL;   // last element of d_out
    float* llh  = (float*)d_ws;                  // 64 floats of scratch

    emis_kernel<<<(BB * TT) / 64, 64, 0, stream>>>(outputs, fc_w, fc_b, emis);
    crf_kernel<<<BB, 64, 0, stream>>>(emis, start_t, end_t, trans, labels, mask, llh);
    loss_kernel<<<1, 64, 0, stream>>>(llh, loss);
}

// Round 2
// 154.143 us; speedup vs baseline: 2.1838x; 2.1838x over previous
//
#include <hip/hip_runtime.h>

#define HID 768
#define NL  17
#define BB  64
#define TT  512

#define SPLIT 8          // waves per block, each owns HID/SPLIT columns
#define CHUNK 96         // HID / SPLIT
#define PADL  65         // 64 + 1 pad: bank = (65*k + r) % 32 varies with k

// ---------------------------------------------------------------------------
// Kernel 1: emissions = outputs @ fc_w^T + fc_b
// Block = 512 threads (8 waves) handles 64 rows. Wave s computes partial dots
// over columns [s*96, s*96+96); partials reduced through padded LDS.
// ---------------------------------------------------------------------------
__global__ __launch_bounds__(512) void emis_kernel(const float* __restrict__ x,
                                                   const float* __restrict__ w,
                                                   const float* __restrict__ bias,
                                                   float* __restrict__ y) {
    __shared__ float pacc[SPLIT][NL][PADL];

    const int lane = threadIdx.x & 63;
    const int wid  = threadIdx.x >> 6;                 // 0..7
    const int row  = blockIdx.x * 64 + lane;
    const float* rp = x + (size_t)row * HID + wid * CHUNK;

    float acc[NL];
#pragma unroll
    for (int k = 0; k < NL; ++k) acc[k] = 0.f;

#pragma unroll
    for (int pass = 0; pass < 2; ++pass) {
        float4 r[12];
#pragma unroll
        for (int u = 0; u < 12; ++u)
            r[u] = *reinterpret_cast<const float4*>(rp + pass * 48 + u * 4);
#pragma unroll
        for (int k = 0; k < NL; ++k) {
            const float* wp = w + k * HID + wid * CHUNK + pass * 48;
            float s0 = 0.f, s1 = 0.f, s2 = 0.f, s3 = 0.f;
#pragma unroll
            for (int u = 0; u < 12; ++u) {
                const float4 wv = *reinterpret_cast<const float4*>(wp + u * 4);
                s0 = fmaf(r[u].x, wv.x, s0);
                s1 = fmaf(r[u].y, wv.y, s1);
                s2 = fmaf(r[u].z, wv.z, s2);
                s3 = fmaf(r[u].w, wv.w, s3);
            }
            acc[k] += (s0 + s1) + (s2 + s3);
        }
    }

#pragma unroll
    for (int k = 0; k < NL; ++k) pacc[wid][k][lane] = acc[k];
    __syncthreads();

    // reduce SPLIT partials; outputs are contiguous: y[blk*1088 + o]
    for (int o = threadIdx.x; o < 64 * NL; o += 512) {
        const int r = o / NL, k = o % NL;
        float s = bias[k];
#pragma unroll
        for (int sp = 0; sp < SPLIT; ++sp) s += pacc[sp][k][r];
        y[(size_t)blockIdx.x * (64 * NL) + o] = s;
    }
}

// ---------------------------------------------------------------------------
// Kernel 2: per-batch CRF log-likelihood. One wave (64 threads) per batch.
// Forward scan in the exp domain: p' = (E^t p) * exp(em_t), E^t = exp(trans).
// ---------------------------------------------------------------------------
__device__ __forceinline__ float bcast(float v, int lane) {
    return __uint_as_float(__builtin_amdgcn_readlane(__float_as_uint(v), lane));
}

__global__ __launch_bounds__(64) void crf_kernel(const float* __restrict__ emis,
                                                 const float* __restrict__ start_t,
                                                 const float* __restrict__ end_t,
                                                 const float* __restrict__ trans,
                                                 const int* __restrict__ labels,
                                                 const int* __restrict__ mask,
                                                 float* __restrict__ llh) {
    __shared__ float em_s[TT * NL];      // 34.8 KB: this batch's emissions
    __shared__ float trans_s[NL * NL];

    const int b = blockIdx.x;
    const int l = threadIdx.x;

    // stage emissions + trans into LDS (coalesced float4 copies)
    const float4* eb4 = reinterpret_cast<const float4*>(emis + (size_t)b * TT * NL);
    float4* em4 = reinterpret_cast<float4*>(em_s);
    for (int i = l; i < TT * NL / 4; i += 64) em4[i] = eb4[i];
    for (int i = l; i < NL * NL; i += 64) trans_s[i] = trans[i];
    __syncthreads();

    // sequence length (mask is a prefix; reference forces mask[:,0]=True)
    int lenp = 0;
    for (int i = l; i < TT; i += 64) lenp += (mask[b * TT + i] != 0);
#pragma unroll
    for (int off = 32; off; off >>= 1) lenp += __shfl_down(lenp, off);
    const int len = __shfl(lenp, 0);

    // ---------------- numerator ----------------
    float np = 0.f;
    for (int t = l; t < len; t += 64) {
        int tag = labels[b * TT + t];
        if (tag < 0 || tag >= NL) tag = 0;
        if (t == 0) {
            np += start_t[tag] + em_s[tag];
        } else {
            int tp = labels[b * TT + t - 1];
            if (tp < 0 || tp >= NL) tp = 0;
            np += trans_s[tp * NL + tag] + em_s[t * NL + tag];
        }
        if (t == len - 1) np += end_t[tag];
    }
#pragma unroll
    for (int off = 32; off; off >>= 1) np += __shfl_down(np, off);
    const float num = __shfl(np, 0);

    // ---------------- denominator: forward scan, exp domain ----------------
    const bool act = (l < NL);
    const int  j   = act ? l : 0;

    float et[NL];                        // exp(trans[i][j]) for my column j
#pragma unroll
    for (int i = 0; i < NL; ++i) et[i] = __expf(trans_s[i * NL + j]);

    float p = act ? __expf(start_t[j] + em_s[j]) : 0.f;   // score[0][j], exp domain
    float M = 0.f;                                        // accumulated log offset

    for (int t = 1; t < len; ++t) {
        const float eem = act ? __expf(em_s[t * NL + j]) : 0.f;
        float q0 = 0.f, q1 = 0.f, q2 = 0.f, q3 = 0.f;
#pragma unroll
        for (int i = 0; i < 16; i += 4) {
            q0 = fmaf(bcast(p, i + 0), et[i + 0], q0);
            q1 = fmaf(bcast(p, i + 1), et[i + 1], q1);
            q2 = fmaf(bcast(p, i + 2), et[i + 2], q2);
            q3 = fmaf(bcast(p, i + 3), et[i + 3], q3);
        }
        q0 = fmaf(bcast(p, 16), et[16], q0);
        p = ((q0 + q1) + (q2 + q3)) * eem;

        if ((t & 3) == 0) {              // renormalize every 4 steps
            const float p0 = bcast(p, 0);
            M += __logf(p0);
            p *= __frcp_rn(p0);
        }
    }

    float v = act ? p * __expf(end_t[j]) : 0.f;
#pragma unroll
    for (int off = 32; off; off >>= 1) v += __shfl_down(v, off);

    if (l == 0) {
        const float denom = M + __logf(v);
        llh[b] = num - denom;
    }
}

// ---------------------------------------------------------------------------
// Kernel 3: loss = -mean(llh)
// ---------------------------------------------------------------------------
__global__ __launch_bounds__(64) void loss_kernel(const float* __restrict__ llh,
                                                  float* __restrict__ loss) {
    float v = llh[threadIdx.x];
#pragma unroll
    for (int off = 32; off; off >>= 1) v += __shfl_down(v, off);
    if (threadIdx.x == 0) loss[0] = -(v * (1.0f / BB));
}

// ---------------------------------------------------------------------------
extern "C" void kernel_launch(void* const* d_in, const int* in_sizes, int n_in,
                              void* d_out, int out_size, void* d_ws, size_t ws_size,
                              hipStream_t stream) {
    const float* outputs = (const float*)d_in[0];
    const float* fc_w    = (const float*)d_in[1];
    const float* fc_b    = (const float*)d_in[2];
    const float* start_t = (const float*)d_in[3];
    const float* end_t   = (const float*)d_in[4];
    const float* trans   = (const float*)d_in[5];
    const int*   labels  = (const int*)d_in[6];
    const int*   mask    = (const int*)d_in[7];

    float* emis = (float*)d_out;
    float* loss = emis + (size_t)BB * TT * NL;   // last element of d_out
    float* llh  = (float*)d_ws;                  // 64 floats of scratch

    emis_kernel<<<(BB * TT) / 64, 512, 0, stream>>>(outputs, fc_w, fc_b, emis);
    crf_kernel<<<BB, 64, 0, stream>>>(emis, start_t, end_t, trans, labels, mask, llh);
    loss_kernel<<<1, 64, 0, stream>>>(llh, loss);
}